// Round 7
// baseline (36.149 us; speedup 1.0000x reference)
//
#include <hip/hip_runtime.h>
#include <hip/hip_bf16.h>

// Problem constants (fixed by the reference setup)
#define Nn 2
#define Tt 8
#define Cc 3
#define Hh 128
#define Ww 128
#define Dd 64
#define NT (Nn * Tt)
#define HW (Hh * Ww)

typedef float f32x4 __attribute__((ext_vector_type(4)));  // native vector for nontemporal store

// ---------------------------------------------------------------------------
// Fused kernel, block-uniform setup done once per block (thread 0 -> LDS).
// Homography factors as a rank-1 update:
//   Hg(nt,d) = KR·refM - (KR·diff)·(nr^T·refM)/depth = W0 - u·v^T/dep
// Then 4 px/thread, division-free validity gate (|n0| <= 1.02|n2| + eps;
// true bound 1.0078 from the reference's [-1,1]-grid-on-pixel-coords quirk),
// heavy bilinear path only near the valid locus, nontemporal float4 stores
// (output streams 201 MB through L2 -> keep images cached instead).
// grid = (HW/1024, D, NT), block = 256
// ---------------------------------------------------------------------------
__global__ __launch_bounds__(256) void homog_fused(
    const float* __restrict__ images,  // (NT,C,H,W)
    const float* __restrict__ intr,    // (N,T,3,3)
    const float* __restrict__ extr,    // (N,T,4,4)
    const float* __restrict__ depths,  // (D,)
    float* __restrict__ out)           // (NT,C,D,H,W)
{
    const int d  = blockIdx.y;
    const int nt = blockIdx.z;

    __shared__ float Ms[9];

    if (threadIdx.x == 0) {
        const int n = nt >> 3;                      // Tt == 8
        const float* Kv = intr + nt * 9;
        const float* Kr = intr + (n * Tt) * 9;      // intrinsics[n,0]
        const float* Ev = extr + nt * 16;
        const float* Er = extr + (n * Tt) * 16;     // extrinsics[n,0]

        float Rr[3][3], Rv[3][3], tr[3], tv[3];
        #pragma unroll
        for (int i = 0; i < 3; ++i) {
            #pragma unroll
            for (int j = 0; j < 3; ++j) {
                Rr[i][j] = Er[i * 4 + j];
                Rv[i][j] = Ev[i * 4 + j];
            }
            tr[i] = Er[i * 4 + 3];
            tv[i] = Ev[i * 4 + 3];
        }

        float diff[3];
        #pragma unroll
        for (int i = 0; i < 3; ++i) {
            float a = Rr[0][i] * tr[0] + Rr[1][i] * tr[1] + Rr[2][i] * tr[2];
            float b = Rv[0][i] * tv[0] + Rv[1][i] * tv[1] + Rv[2][i] * tv[2];
            diff[i] = a - b;
        }
        float nr[3] = {Rr[2][0], Rr[2][1], Rr[2][2]};

        // inv(K_ref) via adjugate
        float k0 = Kr[0], k1 = Kr[1], k2 = Kr[2];
        float k3 = Kr[3], k4 = Kr[4], k5 = Kr[5];
        float k6 = Kr[6], k7 = Kr[7], k8 = Kr[8];
        float c00 = k4 * k8 - k5 * k7;
        float c01 = k5 * k6 - k3 * k8;
        float c02 = k3 * k7 - k4 * k6;
        float det = k0 * c00 + k1 * c01 + k2 * c02;
        float invd = 1.0f / det;
        float iK[3][3];
        iK[0][0] = c00 * invd;
        iK[0][1] = (k2 * k7 - k1 * k8) * invd;
        iK[0][2] = (k1 * k5 - k2 * k4) * invd;
        iK[1][0] = c01 * invd;
        iK[1][1] = (k0 * k8 - k2 * k6) * invd;
        iK[1][2] = (k2 * k3 - k0 * k5) * invd;
        iK[2][0] = c02 * invd;
        iK[2][1] = (k1 * k6 - k0 * k7) * invd;
        iK[2][2] = (k0 * k4 - k1 * k3) * invd;

        float refM[3][3], KR[3][3];
        #pragma unroll
        for (int i = 0; i < 3; ++i)
            #pragma unroll
            for (int j = 0; j < 3; ++j) {
                refM[i][j] = Rr[i][0] * iK[0][j] + Rr[i][1] * iK[1][j] + Rr[i][2] * iK[2][j];
                KR[i][j]   = Kv[i * 3 + 0] * Rv[0][j] + Kv[i * 3 + 1] * Rv[1][j] + Kv[i * 3 + 2] * Rv[2][j];
            }

        float W0[3][3], u[3], v[3];
        #pragma unroll
        for (int i = 0; i < 3; ++i) {
            #pragma unroll
            for (int j = 0; j < 3; ++j)
                W0[i][j] = KR[i][0] * refM[0][j] + KR[i][1] * refM[1][j] + KR[i][2] * refM[2][j];
            u[i] = KR[i][0] * diff[0] + KR[i][1] * diff[1] + KR[i][2] * diff[2];
            v[i] = refM[0][i] * nr[0] + refM[1][i] * nr[1] + refM[2][i] * nr[2];
        }

        const float rdep = __builtin_amdgcn_rcpf(depths[d]);
        #pragma unroll
        for (int i = 0; i < 3; ++i) {
            float ui = u[i] * rdep;
            #pragma unroll
            for (int j = 0; j < 3; ++j)
                Ms[i * 3 + j] = W0[i][j] - ui * v[j];
        }
    }
    __syncthreads();

    const float m0 = Ms[0], m1 = Ms[1], m2 = Ms[2];
    const float m3 = Ms[3], m4 = Ms[4], m5 = Ms[5];
    const float m6 = Ms[6], m7 = Ms[7], m8 = Ms[8];

    const int q  = blockIdx.x * 256 + threadIdx.x;  // quad index
    const int p0 = q << 2;
    const int h  = p0 >> 7;                         // Ww == 128
    const int w  = p0 & 127;

    // Reference quirk: coords = (h + 0.5, w + 0.5, 1)
    const float xc = (float)h + 0.5f;
    const float yc = (float)w + 0.5f;
    const float n0 = fmaf(m1, yc, fmaf(m0, xc, m2));
    const float n1 = fmaf(m4, yc, fmaf(m3, xc, m5));
    const float n2 = fmaf(m7, yc, fmaf(m6, xc, m8));

    float r0[4], r1[4], r2[4];
    #pragma unroll
    for (int k = 0; k < 4; ++k) { r0[k] = 0.0f; r1[k] = 0.0f; r2[k] = 0.0f; }

    // ---- cheap division-free gate over the 4 pixels ----
    bool poss[4];
    {
        float a0 = n0, a1 = n1, a2 = n2;
        #pragma unroll
        for (int k = 0; k < 4; ++k) {
            float t = fmaf(1.02f, fabsf(a2), 1e-6f);
            poss[k] = (fabsf(a0) <= t) && (fabsf(a1) <= t);
            a0 += m1; a1 += m4; a2 += m7;
        }
    }

    if (poss[0] || poss[1] || poss[2] || poss[3]) {
        const float* img = images + nt * (Cc * HW);
        float a0 = n0, a1 = n1, a2 = n2;
        #pragma unroll
        for (int k = 0; k < 4; ++k) {
            if (poss[k]) {
                float z  = (a2 == 0.0f) ? 1e-7f : a2;
                float rz = __builtin_amdgcn_rcpf(z);
                float gx = ((a0 * rz + 1.0f) * (float)Ww - 1.0f) * 0.5f;
                float gy = ((a1 * rz + 1.0f) * (float)Hh - 1.0f) * 0.5f;

                float x0f = floorf(gx), y0f = floorf(gy);
                float x1f = x0f + 1.0f, y1f = y0f + 1.0f;
                float wx1 = gx - x0f, wx0 = 1.0f - wx1;
                float wy1 = gy - y0f, wy0 = 1.0f - wy1;

                float v00 = (x0f >= 0.0f && x0f <= 127.0f && y0f >= 0.0f && y0f <= 127.0f) ? 1.0f : 0.0f;
                float v10 = (x1f >= 0.0f && x1f <= 127.0f && y0f >= 0.0f && y0f <= 127.0f) ? 1.0f : 0.0f;
                float v01 = (x0f >= 0.0f && x0f <= 127.0f && y1f >= 0.0f && y1f <= 127.0f) ? 1.0f : 0.0f;
                float v11 = (x1f >= 0.0f && x1f <= 127.0f && y1f >= 0.0f && y1f <= 127.0f) ? 1.0f : 0.0f;

                float w00 = (wx0 * wy0) * v00;
                float w10 = (wx1 * wy0) * v10;
                float w01 = (wx0 * wy1) * v01;
                float w11 = (wx1 * wy1) * v11;

                if (w00 != 0.0f || w10 != 0.0f || w01 != 0.0f || w11 != 0.0f) {
                    int xi0 = (int)fminf(fmaxf(x0f, 0.0f), 127.0f);
                    int xi1 = (int)fminf(fmaxf(x1f, 0.0f), 127.0f);
                    int yi0 = (int)fminf(fmaxf(y0f, 0.0f), 127.0f);
                    int yi1 = (int)fminf(fmaxf(y1f, 0.0f), 127.0f);
                    int i00 = yi0 * Ww + xi0;
                    int i10 = yi0 * Ww + xi1;
                    int i01 = yi1 * Ww + xi0;
                    int i11 = yi1 * Ww + xi1;
                    r0[k] = img[i00] * w00 + img[i10] * w10 + img[i01] * w01 + img[i11] * w11;
                    r1[k] = img[HW + i00] * w00 + img[HW + i10] * w10 + img[HW + i01] * w01 + img[HW + i11] * w11;
                    r2[k] = img[2 * HW + i00] * w00 + img[2 * HW + i10] * w10 + img[2 * HW + i01] * w01 + img[2 * HW + i11] * w11;
                }
            }
            a0 += m1; a1 += m4; a2 += m7;   // next pixel: yc += 1
        }
    }

    size_t obase = ((size_t)(nt * Cc) * Dd + d) * HW + p0;
    f32x4* o0 = reinterpret_cast<f32x4*>(&out[obase]);
    f32x4* o1 = reinterpret_cast<f32x4*>(&out[obase + (size_t)Dd * HW]);
    f32x4* o2 = reinterpret_cast<f32x4*>(&out[obase + (size_t)2 * Dd * HW]);
    f32x4 s0 = {r0[0], r0[1], r0[2], r0[3]};
    f32x4 s1 = {r1[0], r1[1], r1[2], r1[3]};
    f32x4 s2 = {r2[0], r2[1], r2[2], r2[3]};
    __builtin_nontemporal_store(s0, o0);
    __builtin_nontemporal_store(s1, o1);
    __builtin_nontemporal_store(s2, o2);
}

extern "C" void kernel_launch(void* const* d_in, const int* in_sizes, int n_in,
                              void* d_out, int out_size, void* d_ws, size_t ws_size,
                              hipStream_t stream) {
    const float* images = (const float*)d_in[0];
    const float* intr   = (const float*)d_in[1];
    const float* extr   = (const float*)d_in[2];
    const float* depths = (const float*)d_in[3];
    float* out = (float*)d_out;

    homog_fused<<<dim3(HW / 1024, Dd, NT), dim3(256), 0, stream>>>(
        images, intr, extr, depths, out);
}